// Round 3
// baseline (1085.890 us; speedup 1.0000x reference)
//
#include <hip/hip_runtime.h>
#include <cstdint>

typedef unsigned short u16;
typedef unsigned int   u32;
typedef u16   u16x8 __attribute__((ext_vector_type(8)));
typedef float f32x4 __attribute__((ext_vector_type(4)));
typedef __bf16 bf16x8 __attribute__((ext_vector_type(8)));

#define NB    256      // windows (16x16 grid)
#define WTOK  49       // tokens per window (7x7)
#define CH    512
#define HEADS 8
#define DH    64
#define TOK   100352   // 8*256*49
#define CO    1536

// ---------- helpers ----------
__device__ __forceinline__ u16 f2bf(float f) {
  u32 u = __float_as_uint(f);
  u = (u + 0x7FFFu + ((u >> 16) & 1u)) >> 16;
  return (u16)u;
}
__device__ __forceinline__ float bf2f(u16 u) { return __uint_as_float(((u32)u) << 16); }

__device__ __forceinline__ void load_lds16(const void* g, void* l) {
  __builtin_amdgcn_global_load_lds(
      reinterpret_cast<__attribute__((address_space(1))) void*>(reinterpret_cast<uintptr_t>(g)),
      reinterpret_cast<__attribute__((address_space(3))) void*>(reinterpret_cast<uintptr_t>(l)),
      16, 0, 0);
}

// ---------- small prep kernels ----------
__global__ void cvt_f32_bf16(const float* __restrict__ in, u16* __restrict__ out, int n8) {
  int i = blockIdx.x * 256 + threadIdx.x;
  if (i < n8) {
    f32x4 a = *(const f32x4*)(in + (long)i * 8);
    f32x4 b = *(const f32x4*)(in + (long)i * 8 + 4);
    u16x8 o;
    o[0]=f2bf(a[0]); o[1]=f2bf(a[1]); o[2]=f2bf(a[2]); o[3]=f2bf(a[3]);
    o[4]=f2bf(b[0]); o[5]=f2bf(b[1]); o[6]=f2bf(b[2]); o[7]=f2bf(b[3]);
    *(u16x8*)(out + (long)i * 8) = o;
  }
}

__global__ void prep_wle(const float* __restrict__ lepe_w, float* __restrict__ wle) {
  int i = blockIdx.x * 256 + threadIdx.x;   // 12800 = 512*25
  if (i < 12800) {
    int c = i / 25, kk = i % 25;
    wle[kk * 512 + c] = lepe_w[i];
  }
}

// block-weight matrix: mat[i,j] = cos(d(i,j)/dmax * pi/4), column-normalized over i
__global__ void weight_kernel(u16* __restrict__ Wbf, float* __restrict__ Wt) {
  int j = blockIdx.x, i = threadIdx.x;
  float iy = (float)(i >> 4) + 0.5f, ix = (float)(i & 15) + 0.5f;
  float jy = (float)(j >> 4) + 0.5f, jx = (float)(j & 15) + 0.5f;
  float dy = iy - jy, dx = ix - jx;
  float d = sqrtf(dy * dy + dx * dx);
  const float dmax = 21.213203435596427f;           // sqrt(450)
  float m = cosf(d * (0.78539816339744831f / dmax)); // pi/4 / dmax
  __shared__ float red[256];
  red[i] = m;
  __syncthreads();
  for (int s = 128; s > 0; s >>= 1) {
    if (i < s) red[i] += red[i + s];
    __syncthreads();
  }
  float w = m / red[0];
  Wbf[i * 256 + j] = f2bf(w);
  Wt[j * 256 + i] = w;
}

// ---------- LayerNorm (wave per token) ----------
__global__ __launch_bounds__(256) void ln_kernel(const float* __restrict__ x,
                                                 const float* __restrict__ g,
                                                 const float* __restrict__ bta,
                                                 u16* __restrict__ xn) {
  int wave = threadIdx.x >> 6, lane = threadIdx.x & 63;
  long t = (long)blockIdx.x * 4 + wave;
  const float* xp = x + t * CH + lane * 8;
  f32x4 a = *(const f32x4*)xp;
  f32x4 b = *(const f32x4*)(xp + 4);
  float s  = a[0]+a[1]+a[2]+a[3]+b[0]+b[1]+b[2]+b[3];
  float sq = a[0]*a[0]+a[1]*a[1]+a[2]*a[2]+a[3]*a[3]+b[0]*b[0]+b[1]*b[1]+b[2]*b[2]+b[3]*b[3];
  for (int m = 1; m < 64; m <<= 1) { s += __shfl_xor(s, m); sq += __shfl_xor(sq, m); }
  float mu = s * (1.0f / 512.0f);
  float var = sq * (1.0f / 512.0f) - mu * mu;
  float rstd = rsqrtf(var + 1e-5f);
  const float* gp = g + lane * 8;
  const float* bp = bta + lane * 8;
  f32x4 g0 = *(const f32x4*)gp, g1 = *(const f32x4*)(gp + 4);
  f32x4 b0 = *(const f32x4*)bp, b1 = *(const f32x4*)(bp + 4);
  u16x8 o;
  o[0] = f2bf((a[0]-mu)*rstd*g0[0] + b0[0]);
  o[1] = f2bf((a[1]-mu)*rstd*g0[1] + b0[1]);
  o[2] = f2bf((a[2]-mu)*rstd*g0[2] + b0[2]);
  o[3] = f2bf((a[3]-mu)*rstd*g0[3] + b0[3]);
  o[4] = f2bf((b[0]-mu)*rstd*g1[0] + b1[0]);
  o[5] = f2bf((b[1]-mu)*rstd*g1[1] + b1[1]);
  o[6] = f2bf((b[2]-mu)*rstd*g1[2] + b1[2]);
  o[7] = f2bf((b[3]-mu)*rstd*g1[3] + b1[3]);
  *(u16x8*)(xn + t * CH + lane * 8) = o;
}

// ================= 8-phase 256x256 GEMM, K=512 fixed =================
template <int KT>
__device__ __forceinline__ void kstep8(char* sm, const u16* sA, const u16* sB,
                                       int t, int lane_off, int wm, int wn,
                                       f32x4 (&acc)[8][4]) {
  const char* base = sm + (KT & 3) * 32768 + lane_off;
  char* wbp = sm + ((KT + 3) & 3) * 32768 + t * 16;
  if constexpr (KT + 3 < 16) {
    load_lds16(sA + (KT + 3) * 32, wbp);
    load_lds16(sA + (KT + 3) * 32 + 65536, wbp + 8192);
  }
  bf16x8 bfr[4], afr[4];
#pragma unroll
  for (int n = 0; n < 4; n++) bfr[n] = *(const bf16x8*)(base + 16384 + wn * 4096 + n * 1024);
#pragma unroll
  for (int m = 0; m < 4; m++) afr[m] = *(const bf16x8*)(base + wm * 8192 + m * 1024);
  __builtin_amdgcn_s_barrier();
  __builtin_amdgcn_s_setprio(1);
#pragma unroll
  for (int m = 0; m < 4; m++)
#pragma unroll
    for (int n = 0; n < 4; n++)
      acc[m][n] = __builtin_amdgcn_mfma_f32_16x16x32_bf16(afr[m], bfr[n], acc[m][n], 0, 0, 0);
  __builtin_amdgcn_s_setprio(0);
  __builtin_amdgcn_s_barrier();
  if constexpr (KT + 3 < 16) {
    load_lds16(sB + (KT + 3) * 32, wbp + 16384);
    load_lds16(sB + (KT + 3) * 32 + 65536, wbp + 24576);
  }
#pragma unroll
  for (int m = 0; m < 4; m++) afr[m] = *(const bf16x8*)(base + wm * 8192 + (4 + m) * 1024);
  __builtin_amdgcn_s_barrier();
  __builtin_amdgcn_s_setprio(1);
#pragma unroll
  for (int m = 0; m < 4; m++)
#pragma unroll
    for (int n = 0; n < 4; n++)
      acc[4 + m][n] = __builtin_amdgcn_mfma_f32_16x16x32_bf16(afr[m], bfr[n], acc[4 + m][n], 0, 0, 0);
  __builtin_amdgcn_s_setprio(0);
  if constexpr (KT < 13) {
    asm volatile("s_waitcnt vmcnt(8)" ::: "memory");
  } else if constexpr (KT == 13) {
    asm volatile("s_waitcnt vmcnt(4)" ::: "memory");
  } else if constexpr (KT == 14) {
    asm volatile("s_waitcnt vmcnt(0)" ::: "memory");
  }
  if constexpr (KT < 15) __builtin_amdgcn_s_barrier();
}

// EPI: 0 = bf16 out, 1 = bf16 out with relu+1e-6 on cols<1024, 2 = f32 out + bias
template <int EPI>
__global__ __launch_bounds__(512, 2)
void gemm8(const u16* __restrict__ A, const u16* __restrict__ B,
           void* __restrict__ C, const float* __restrict__ bias, int N, int nbn) {
  __shared__ __align__(16) char sm[131072];
  const int nwg = gridDim.x;
  const int bid = blockIdx.x;
  const int cpx = nwg >> 3;
  const int vid = (bid & 7) * cpx + (bid >> 3);   // XCD-contiguous chunks
  const int bn = vid % nbn, bm = vid / nbn;
  const int t = threadIdx.x;
  const int lane = t & 63, wave = t >> 6;
  const int wm = wave >> 2, wn = wave & 3;
  const int fr = lane & 15, fq = lane >> 4;
  const int lane_off = (fr >> 1) * 128 + ((((fr & 1) << 2) + fq) ^ (fr >> 1)) * 16;
  const int sl = (t & 7) ^ ((t >> 3) & 7);
  const u16* sA = A + ((long)bm * 256 + ((t >> 3) << 1) + (sl >> 2)) * 512 + (sl & 3) * 8;
  const u16* sB = B + ((long)bn * 256 + ((t >> 3) << 1) + (sl >> 2)) * 512 + (sl & 3) * 8;
  f32x4 acc[8][4] = {};
#pragma unroll
  for (int kt = 0; kt < 3; kt++) {
    char* d = sm + kt * 32768 + t * 16;
    load_lds16(sA + kt * 32, d);
    load_lds16(sA + kt * 32 + 65536, d + 8192);
    load_lds16(sB + kt * 32, d + 16384);
    load_lds16(sB + kt * 32 + 65536, d + 24576);
  }
  asm volatile("s_waitcnt vmcnt(8)" ::: "memory");
  __builtin_amdgcn_s_barrier();
  kstep8<0>(sm, sA, sB, t, lane_off, wm, wn, acc);
  kstep8<1>(sm, sA, sB, t, lane_off, wm, wn, acc);
  kstep8<2>(sm, sA, sB, t, lane_off, wm, wn, acc);
  kstep8<3>(sm, sA, sB, t, lane_off, wm, wn, acc);
  kstep8<4>(sm, sA, sB, t, lane_off, wm, wn, acc);
  kstep8<5>(sm, sA, sB, t, lane_off, wm, wn, acc);
  kstep8<6>(sm, sA, sB, t, lane_off, wm, wn, acc);
  kstep8<7>(sm, sA, sB, t, lane_off, wm, wn, acc);
  kstep8<8>(sm, sA, sB, t, lane_off, wm, wn, acc);
  kstep8<9>(sm, sA, sB, t, lane_off, wm, wn, acc);
  kstep8<10>(sm, sA, sB, t, lane_off, wm, wn, acc);
  kstep8<11>(sm, sA, sB, t, lane_off, wm, wn, acc);
  kstep8<12>(sm, sA, sB, t, lane_off, wm, wn, acc);
  kstep8<13>(sm, sA, sB, t, lane_off, wm, wn, acc);
  kstep8<14>(sm, sA, sB, t, lane_off, wm, wn, acc);
  kstep8<15>(sm, sA, sB, t, lane_off, wm, wn, acc);
  const long r0 = (long)bm * 256 + wm * 128 + fq * 4;
  const int c0 = bn * 256 + wn * 64 + fr;
#pragma unroll
  for (int m = 0; m < 8; m++) {
#pragma unroll
    for (int n = 0; n < 4; n++) {
      int c = c0 + n * 16;
#pragma unroll
      for (int jj = 0; jj < 4; jj++) {
        long r = r0 + m * 16 + jj;
        float v = acc[m][n][jj];
        if (EPI == 1) {
          if (c < 1024) v = fmaxf(v, 0.0f) + 1e-6f;
          ((u16*)C)[r * N + c] = f2bf(v);
        } else if (EPI == 2) {
          ((float*)C)[r * N + c] = v + bias[c];
        } else {
          ((u16*)C)[r * N + c] = f2bf(v);
        }
      }
    }
  }
}

// ---------- m97-style B^T GEMM (kept for the mix GEMM) ----------
template <int EPI>
__global__ __launch_bounds__(256)
void gemm_bt(const u16* __restrict__ A, const u16* __restrict__ B,
             void* __restrict__ C, const float* __restrict__ bias,
             int M, int N, int K, long sAb, long sBb, long sCb) {
  __shared__ u16 As[128 * 32];
  __shared__ u16 Bs[128 * 32];
  const int tid = threadIdx.x;
  const int lane = tid & 63;
  const int wave = tid >> 6;
  const int fr = lane & 15, fq = lane >> 4;
  const int wr = (wave >> 1) * 64, wc = (wave & 1) * 64;
  const long bm = blockIdx.y, bn = blockIdx.x, bz = blockIdx.z;
  const u16* Ab = A + bz * sAb + bm * 128 * (long)K;
  const u16* Bb = B + bz * sBb + bn * 128 * (long)K;
  const int srow = tid >> 2;
  const int scol = (tid & 3) * 8;
  f32x4 acc[4][4] = {};
  for (int k0 = 0; k0 < K; k0 += 32) {
    load_lds16(Ab + (long)srow * K + k0 + scol, As + tid * 8);
    load_lds16(Ab + (long)(srow + 64) * K + k0 + scol, As + 2048 + tid * 8);
    load_lds16(Bb + (long)srow * K + k0 + scol, Bs + tid * 8);
    load_lds16(Bb + (long)(srow + 64) * K + k0 + scol, Bs + 2048 + tid * 8);
    __syncthreads();
    bf16x8 af[4], bf[4];
#pragma unroll
    for (int m = 0; m < 4; m++) af[m] = *(const bf16x8*)&As[(wr + m * 16 + fr) * 32 + fq * 8];
#pragma unroll
    for (int n = 0; n < 4; n++) bf[n] = *(const bf16x8*)&Bs[(wc + n * 16 + fr) * 32 + fq * 8];
#pragma unroll
    for (int m = 0; m < 4; m++)
#pragma unroll
      for (int n = 0; n < 4; n++)
        acc[m][n] = __builtin_amdgcn_mfma_f32_16x16x32_bf16(af[m], bf[n], acc[m][n], 0, 0, 0);
    __syncthreads();
  }
#pragma unroll
  for (int m = 0; m < 4; m++) {
    int r0 = wr + m * 16 + fq * 4;
#pragma unroll
    for (int n = 0; n < 4; n++) {
      int c = (int)bn * 128 + wc + n * 16 + fr;
#pragma unroll
      for (int jj = 0; jj < 4; jj++) {
        long r = bm * 128 + r0 + jj;
        float v = acc[m][n][jj];
        if (EPI == 1) { if (c < 1024) v = fmaxf(v, 0.0f) + 1e-6f; }
        if (EPI == 2) {
          ((float*)C)[bz * sCb + r * N + c] = v + bias[c];
        } else {
          ((u16*)C)[bz * sCb + r * N + c] = f2bf(v);
        }
      }
    }
  }
}

// ---------- fold v into zero-padded image [8][116][116][512] ----------
__global__ __launch_bounds__(256)
void fold_v(const u16* __restrict__ qkv, u16* __restrict__ vimg) {
  long i = (long)blockIdx.x * 256 + threadIdx.x;  // 25088 blocks
  int tok = (int)(i >> 6);
  int c0 = ((int)i & 63) * 8;
  int w = tok % WTOK, n = tok / WTOK;
  int b = n >> 8, blk = n & 255;
  int gi = blk >> 4, gj = blk & 15;
  int wi = w / 7, wj = w - wi * 7;
  int y = gi * 7 + wi + 2, x = gj * 7 + wj + 2;
  u16x8 v = *(const u16x8*)(qkv + (long)tok * CO + 1024 + c0);
  *(u16x8*)(vimg + (((long)(b * 116 + y)) * 116 + x) * 512 + c0) = v;
}

// zero the 2-wide border of vimg
__global__ __launch_bounds__(256)
void zero_border(u16* __restrict__ vimg) {
  int y = blockIdx.x, b = blockIdx.y;
  int tid = threadIdx.x;
  u16* row = vimg + ((long)(b * 116 + y)) * 116 * 512;
  u16x8 z = {};
  if (y < 2 || y >= 114) {
    for (int i = tid; i < 116 * 512 / 8; i += 256) *(u16x8*)(row + i * 8) = z;
  } else {
    int col = tid >> 6;
    int x = (col < 2) ? col : 112 + col;
    *(u16x8*)(row + x * 512 + (tid & 63) * 8) = z;
  }
}

// ---------- LePE depthwise 5x5 conv on padded image (branch-free) ----------
__global__ __launch_bounds__(256)
void lepe_conv2(const u16* __restrict__ vimg, const float* __restrict__ wle,
                const float* __restrict__ lb, u16* __restrict__ lepe) {
  int b = blockIdx.z, y = blockIdx.y;     // y in [0,112)
  int tid = threadIdx.x;
  int c0 = (tid & 63) * 8;
  int x = blockIdx.x * 4 + (tid >> 6);    // x in [0,112)
  float acc[8];
  {
    f32x4 b0 = *(const f32x4*)(lb + c0);
    f32x4 b1 = *(const f32x4*)(lb + c0 + 4);
#pragma unroll
    for (int i = 0; i < 4; i++) { acc[i] = b0[i]; acc[4 + i] = b1[i]; }
  }
  const u16* base = vimg + (((long)(b * 116 + y)) * 116 + x) * 512 + c0;
#pragma unroll
  for (int ky = 0; ky < 5; ky++) {
#pragma unroll
    for (int kx = 0; kx < 5; kx++) {
      u16x8 v8 = *(const u16x8*)(base + ((long)ky * 116 + kx) * 512);
      const float* wp = wle + (ky * 5 + kx) * 512 + c0;
      f32x4 w0 = *(const f32x4*)wp, w1 = *(const f32x4*)(wp + 4);
#pragma unroll
      for (int i = 0; i < 4; i++) {
        acc[i] += bf2f(v8[i]) * w0[i];
        acc[4 + i] += bf2f(v8[4 + i]) * w1[i];
      }
    }
  }
  int gi = y / 7, wi = y - gi * 7;
  int gj = x / 7, wj = x - gj * 7;
  long tok0 = ((long)(b * NB + gi * 16 + gj)) * WTOK + wi * 7 + wj;
  u16x8 o;
#pragma unroll
  for (int i = 0; i < 8; i++) o[i] = f2bf(acc[i]);
  *(u16x8*)(lepe + tok0 * CH + c0) = o;
}

// ---------- per-window k^T v (MFMA) + k_sum + q·k_sum ----------
__global__ __launch_bounds__(256)
void kv_local_kernel(const u16* __restrict__ qkv, u16* __restrict__ KVl,
                     float* __restrict__ qk_sum) {
  int n = blockIdx.x, h = blockIdx.y, b = blockIdx.z;
  int bh = b * HEADS + h;
  long tbase = ((long)(b * NB + n)) * WTOK;
  __shared__ u16 kT[64 * 72];
  __shared__ u16 vT[64 * 72];
  __shared__ u16 qs[49 * 72];
  __shared__ float ksum[64];
  __shared__ float qkp[256];
  int tid = threadIdx.x;
  for (int i = tid; i < (64 * 72) / 2; i += 256) {
    ((u32*)kT)[i] = 0;
    ((u32*)vT)[i] = 0;
  }
  __syncthreads();
  {
    int w = tid >> 3, d0 = (tid & 7) * 8;
    u16x8 k8 = *(const u16x8*)(qkv + (tbase + w) * CO + 512 + h * 64 + d0);
    u16x8 v8 = *(const u16x8*)(qkv + (tbase + w) * CO + 1024 + h * 64 + d0);
#pragma unroll
    for (int i = 0; i < 8; i++) { kT[(d0 + i) * 72 + w] = k8[i]; vT[(d0 + i) * 72 + w] = v8[i]; }
    int w2 = w + 32;
    if (w2 < WTOK) {
      u16x8 k82 = *(const u16x8*)(qkv + (tbase + w2) * CO + 512 + h * 64 + d0);
      u16x8 v82 = *(const u16x8*)(qkv + (tbase + w2) * CO + 1024 + h * 64 + d0);
#pragma unroll
      for (int i = 0; i < 8; i++) { kT[(d0 + i) * 72 + w2] = k82[i]; vT[(d0 + i) * 72 + w2] = v82[i]; }
    }
    if (tid < 196) {
      int wq = tid >> 2, dq = (tid & 3) * 16;
      u16x8 q0 = *(const u16x8*)(qkv + (tbase + wq) * CO + h * 64 + dq);
      u16x8 q1 = *(const u16x8*)(qkv + (tbase + wq) * CO + h * 64 + dq + 8);
      *(u16x8*)&qs[wq * 72 + dq] = q0;
      *(u16x8*)&qs[wq * 72 + dq + 8] = q1;
    }
  }
  __syncthreads();
  if (tid < 64) {
    float s = 0.0f;
#pragma unroll
    for (int c = 0; c < 9; c++) {
      u16x8 r = *(const u16x8*)&kT[tid * 72 + c * 8];
#pragma unroll
      for (int i = 0; i < 8; i++) s += bf2f(r[i]);
    }
    ksum[tid] = s;
  }
  __syncthreads();
  if (tid < 196) {
    int w = tid >> 2, d0 = (tid & 3) * 16;
    float s = 0.0f;
#pragma unroll
    for (int i = 0; i < 16; i++) s += bf2f(qs[w * 72 + d0 + i]) * ksum[d0 + i];
    qkp[tid] = s;
  }
  __syncthreads();
  if (tid < WTOK) {
    float s = qkp[tid * 4] + qkp[tid * 4 + 1] + qkp[tid * 4 + 2] + qkp[tid * 4 + 3];
    qk_sum[((long)bh * NB + n) * WTOK + tid] = s;
  }
  int lane = tid & 63, wave = tid >> 6;
  int fr = lane & 15, fq = lane >> 4;
  f32x4 acc[4] = {};
#pragma unroll
  for (int ks = 0; ks < 2; ks++) {
    bf16x8 a = *(const bf16x8*)&kT[(wave * 16 + fr) * 72 + ks * 32 + fq * 8];
#pragma unroll
    for (int n4 = 0; n4 < 4; n4++) {
      bf16x8 bb = *(const bf16x8*)&vT[(n4 * 16 + fr) * 72 + ks * 32 + fq * 8];
      acc[n4] = __builtin_amdgcn_mfma_f32_16x16x32_bf16(a, bb, acc[n4], 0, 0, 0);
    }
  }
  long obase = ((long)bh * NB + n) * 4096;
#pragma unroll
  for (int n4 = 0; n4 < 4; n4++)
#pragma unroll
    for (int jj = 0; jj < 4; jj++) {
      int d = wave * 16 + fq * 4 + jj;
      int e = n4 * 16 + fr;
      KVl[obase + d * 64 + e] = f2bf(acc[n4][jj]);
    }
}

// ---------- transpose KVl [bh][256][4096] -> KVT [bh][4096][256] ----------
__global__ __launch_bounds__(256)
void transpose_kv(const u16* __restrict__ in, u16* __restrict__ out) {
  int dt = blockIdx.x, jt = blockIdx.y, bh = blockIdx.z;
  __shared__ u16 t[64 * 72];
  int tid = threadIdx.x;
  {
    int jr = tid >> 2, c0 = (tid & 3) * 16;
    const u16* ip = in + ((long)bh * NB + jt * 64 + jr) * 4096 + dt * 64 + c0;
    *(u16x8*)&t[jr * 72 + c0] = *(const u16x8*)ip;
    *(u16x8*)&t[jr * 72 + c0 + 8] = *(const u16x8*)(ip + 8);
  }
  __syncthreads();
  {
    int der = tid >> 2, j0 = (tid & 3) * 16;
    u16x8 o0, o1;
#pragma unroll
    for (int i = 0; i < 8; i++) o0[i] = t[(j0 + i) * 72 + der];
#pragma unroll
    for (int i = 0; i < 8; i++) o1[i] = t[(j0 + 8 + i) * 72 + der];
    u16* op = out + ((long)bh * 4096 + dt * 64 + der) * 256 + jt * 64 + j0;
    *(u16x8*)op = o0;
    *(u16x8*)(op + 8) = o1;
  }
}

// ---------- normalizer: inv = 1/(Wt^T-mix of qk_sum + eps) ----------
__global__ __launch_bounds__(256)
void norm_kernel(const float* __restrict__ Wt, const float* __restrict__ qk_sum,
                 float* __restrict__ inv_norm) {
  int bh = blockIdx.x, tid = threadIdx.x;
  __shared__ float qk[NB * WTOK];
  for (int i = tid; i < NB * WTOK; i += 256) qk[i] = qk_sum[(long)bh * NB * WTOK + i];
  __syncthreads();
  float acc[WTOK];
#pragma unroll
  for (int w = 0; w < WTOK; w++) acc[w] = 0.0f;
  for (int j = 0; j < NB; j++) {
    float wv = Wt[j * NB + tid];
#pragma unroll
    for (int w = 0; w < WTOK; w++) acc[w] += wv * qk[j * WTOK + w];
  }
  long ob = ((long)bh * NB + tid) * WTOK;
#pragma unroll
  for (int w = 0; w < WTOK; w++) inv_norm[ob + w] = 1.0f / (acc[w] + 1e-6f);
}

// ---------- out = (q @ kvm) * inv_norm + lepe -> ebuf (bf16) ----------
__global__ __launch_bounds__(256)
void attn_out_kernel(const u16* __restrict__ qkv, const u16* __restrict__ kvm,
                     const float* __restrict__ inv_norm, const u16* __restrict__ lepe,
                     u16* __restrict__ ebuf) {
  int n = blockIdx.x, h = blockIdx.y, b = blockIdx.z;
  int bh = b * HEADS + h;
  long tbase = ((long)(b * NB + n)) * WTOK;
  __shared__ u16 qs[64 * 72];
  __shared__ u16 kvT[64 * 72];
  __shared__ float inv[WTOK];
  int tid = threadIdx.x;
  if (tid < 196) {
    int w = tid >> 2, d0 = (tid & 3) * 16;
    u16x8 q0 = *(const u16x8*)(qkv + (tbase + w) * CO + h * 64 + d0);
    u16x8 q1 = *(const u16x8*)(qkv + (tbase + w) * CO + h * 64 + d0 + 8);
    *(u16x8*)&qs[w * 72 + d0] = q0;
    *(u16x8*)&qs[w * 72 + d0 + 8] = q1;
  }
  {
    int d = tid >> 2, e0 = (tid & 3) * 16;
    const u16* kp = kvm + ((long)bh * NB + n) * 4096 + d * 64 + e0;
    u16x8 k0 = *(const u16x8*)kp;
    u16x8 k1 = *(const u16x8*)(kp + 8);
#pragma unroll
    for (int i = 0; i < 8; i++) { kvT[(e0 + i) * 72 + d] = k0[i]; kvT[(e0 + 8 + i) * 72 + d] = k1[i]; }
  }
  if (tid < WTOK) inv[tid] = inv_norm[((long)bh * NB + n) * WTOK + tid];
  __syncthreads();
  int lane = tid & 63, wave = tid >> 6;
  int fr = lane & 15, fq = lane >> 4;
  f32x4 acc[4] = {};
#pragma unroll
  for (int ks = 0; ks < 2; ks++) {
    bf16x8 a = *(const bf16x8*)&qs[(wave * 16 + fr) * 72 + ks * 32 + fq * 8];
#pragma unroll
    for (int n4 = 0; n4 < 4; n4++) {
      bf16x8 bb = *(const bf16x8*)&kvT[(n4 * 16 + fr) * 72 + ks * 32 + fq * 8];
      acc[n4] = __builtin_amdgcn_mfma_f32_16x16x32_bf16(a, bb, acc[n4], 0, 0, 0);
    }
  }
#pragma unroll
  for (int n4 = 0; n4 < 4; n4++)
#pragma unroll
    for (int jj = 0; jj < 4; jj++) {
      int w = wave * 16 + fq * 4 + jj;
      if (w < WTOK) {
        int e = n4 * 16 + fr;
        long off = (tbase + w) * CH + h * 64 + e;
        float v = acc[n4][jj] * inv[w] + bf2f(lepe[off]);
        ebuf[off] = f2bf(v);
      }
    }
}

// ---------- workspace layout ----------
static const size_t OFF_XN    = 0;                         // 102,760,448 (xn, then lepe)
static const size_t OFF_QKV   = 102760448;                 // 308,281,344
static const size_t OFF_KVL   = OFF_QKV + 308281344;       // 134,217,728 (KVl, then kvm)
static const size_t OFF_KVT   = OFF_KVL + 134217728;       // 134,217,728 (vimg, then KVT, then ebuf)
static const size_t OFF_QKS   = OFF_KVT + 134217728;       // 3,211,264
static const size_t OFF_INV   = OFF_QKS + 3211264;         // 3,211,264
static const size_t OFF_WBF   = OFF_INV + 3211264;         // 131,072
static const size_t OFF_WTF   = OFF_WBF + 131072;          // 262,144
static const size_t OFF_WQKVB = OFF_WTF + 262144;          // 1,572,864
static const size_t OFF_WOUTB = OFF_WQKVB + 1572864;       // 524,288
static const size_t OFF_WLE   = OFF_WOUTB + 524288;        // 51,200

extern "C" void kernel_launch(void* const* d_in, const int* in_sizes, int n_in,
                              void* d_out, int out_size, void* d_ws, size_t ws_size,
                              hipStream_t stream) {
  const float* x      = (const float*)d_in[0];
  const float* ln_g   = (const float*)d_in[1];
  const float* ln_b   = (const float*)d_in[2];
  const float* w_qkv  = (const float*)d_in[3];
  const float* lepe_w = (const float*)d_in[4];
  const float* lepe_b = (const float*)d_in[5];
  const float* w_out  = (const float*)d_in[6];
  const float* b_out  = (const float*)d_in[7];
  float* out = (float*)d_out;
  char* ws = (char*)d_ws;

  u16*   xn     = (u16*)(ws + OFF_XN);
  u16*   lepe   = (u16*)(ws + OFF_XN);     // reuse after GEMM1
  u16*   qkv    = (u16*)(ws + OFF_QKV);
  u16*   KVl    = (u16*)(ws + OFF_KVL);
  u16*   kvm    = (u16*)(ws + OFF_KVL);    // reuse after transpose
  u16*   vimg   = (u16*)(ws + OFF_KVT);    // padded v image (110 MB), dead after lepe_conv2
  u16*   KVT    = (u16*)(ws + OFF_KVT);
  u16*   ebuf   = (u16*)(ws + OFF_KVT);    // reuse after mix
  float* qks    = (float*)(ws + OFF_QKS);
  float* invn   = (float*)(ws + OFF_INV);
  u16*   Wbf    = (u16*)(ws + OFF_WBF);
  float* Wt     = (float*)(ws + OFF_WTF);
  u16*   wqkvb  = (u16*)(ws + OFF_WQKVB);
  u16*   woutb  = (u16*)(ws + OFF_WOUTB);
  float* wle    = (float*)(ws + OFF_WLE);

  cvt_f32_bf16<<<384, 256, 0, stream>>>(w_qkv, wqkvb, 98304);
  cvt_f32_bf16<<<128, 256, 0, stream>>>(w_out, woutb, 32768);
  prep_wle<<<50, 256, 0, stream>>>(lepe_w, wle);
  weight_kernel<<<256, 256, 0, stream>>>(Wbf, Wt);
  zero_border<<<dim3(116, 8), 256, 0, stream>>>(vimg);

  ln_kernel<<<25088, 256, 0, stream>>>(x, ln_g, ln_b, xn);

  // qkv = xn @ w_qkv^T, relu+eps on q,k   (8-phase 256x256, K=512)
  gemm8<1><<<2352, 512, 0, stream>>>(xn, wqkvb, (void*)qkv, nullptr, CO, 6);

  fold_v<<<25088, 256, 0, stream>>>(qkv, vimg);
  lepe_conv2<<<dim3(28, 112, 8), 256, 0, stream>>>(vimg, wle, lepe_b, lepe);

  kv_local_kernel<<<dim3(NB, HEADS, 8), 256, 0, stream>>>(qkv, KVl, qks);

  transpose_kv<<<dim3(64, 4, 64), 256, 0, stream>>>(KVl, KVT);

  // kvm[bh] = W @ KV[bh]  (bt-GEMM: A=W [256,256], B=KVT [4096,256])
  gemm_bt<0><<<dim3(32, 2, 64), 256, 0, stream>>>(Wbf, KVT, (void*)kvm, nullptr,
                                                  NB, 4096, NB,
                                                  0, (long)4096 * 256, (long)256 * 4096);

  norm_kernel<<<64, 256, 0, stream>>>(Wt, qks, invn);

  attn_out_kernel<<<dim3(NB, HEADS, 8), 256, 0, stream>>>(qkv, kvm, invn, lepe, ebuf);

  // final projection: out = ebuf @ w_out^T + b_out (fp32 out, 8-phase)
  gemm8<2><<<784, 512, 0, stream>>>(ebuf, woutb, (void*)out, b_out, CH, 2);
}

// Round 4
// 898.808 us; speedup vs baseline: 1.2081x; 1.2081x over previous
//
#include <hip/hip_runtime.h>
#include <cstdint>

typedef unsigned short u16;
typedef unsigned int   u32;
typedef u16   u16x8 __attribute__((ext_vector_type(8)));
typedef u16   u16x4 __attribute__((ext_vector_type(4)));
typedef float f32x4 __attribute__((ext_vector_type(4)));
typedef __bf16 bf16x8 __attribute__((ext_vector_type(8)));

#define NB    256      // windows (16x16 grid)
#define WTOK  49       // tokens per window (7x7)
#define CH    512
#define HEADS 8
#define DH    64
#define TOK   100352   // 8*256*49
#define CO    1536

// ---------- helpers ----------
__device__ __forceinline__ u16 f2bf(float f) {
  u32 u = __float_as_uint(f);
  u = (u + 0x7FFFu + ((u >> 16) & 1u)) >> 16;
  return (u16)u;
}
__device__ __forceinline__ float bf2f(u16 u) { return __uint_as_float(((u32)u) << 16); }

__device__ __forceinline__ void load_lds16(const void* g, void* l) {
  __builtin_amdgcn_global_load_lds(
      reinterpret_cast<__attribute__((address_space(1))) void*>(reinterpret_cast<uintptr_t>(g)),
      reinterpret_cast<__attribute__((address_space(3))) void*>(reinterpret_cast<uintptr_t>(l)),
      16, 0, 0);
}

// ---------- small prep kernels ----------
__global__ void cvt_f32_bf16(const float* __restrict__ in, u16* __restrict__ out, int n8) {
  int i = blockIdx.x * 256 + threadIdx.x;
  if (i < n8) {
    f32x4 a = *(const f32x4*)(in + (long)i * 8);
    f32x4 b = *(const f32x4*)(in + (long)i * 8 + 4);
    u16x8 o;
    o[0]=f2bf(a[0]); o[1]=f2bf(a[1]); o[2]=f2bf(a[2]); o[3]=f2bf(a[3]);
    o[4]=f2bf(b[0]); o[5]=f2bf(b[1]); o[6]=f2bf(b[2]); o[7]=f2bf(b[3]);
    *(u16x8*)(out + (long)i * 8) = o;
  }
}

__global__ void prep_wle(const float* __restrict__ lepe_w, float* __restrict__ wle) {
  int i = blockIdx.x * 256 + threadIdx.x;   // 12800 = 512*25
  if (i < 12800) {
    int c = i / 25, kk = i % 25;
    wle[kk * 512 + c] = lepe_w[i];
  }
}

// block-weight matrix: mat[i,j] = cos(d(i,j)/dmax * pi/4), column-normalized over i
__global__ void weight_kernel(u16* __restrict__ Wbf, float* __restrict__ Wt) {
  int j = blockIdx.x, i = threadIdx.x;
  float iy = (float)(i >> 4) + 0.5f, ix = (float)(i & 15) + 0.5f;
  float jy = (float)(j >> 4) + 0.5f, jx = (float)(j & 15) + 0.5f;
  float dy = iy - jy, dx = ix - jx;
  float d = sqrtf(dy * dy + dx * dx);
  const float dmax = 21.213203435596427f;           // sqrt(450)
  float m = cosf(d * (0.78539816339744831f / dmax)); // pi/4 / dmax
  __shared__ float red[256];
  red[i] = m;
  __syncthreads();
  for (int s = 128; s > 0; s >>= 1) {
    if (i < s) red[i] += red[i + s];
    __syncthreads();
  }
  float w = m / red[0];
  Wbf[i * 256 + j] = f2bf(w);
  Wt[j * 256 + i] = w;
}

// ---------- LayerNorm (wave per token) ----------
__global__ __launch_bounds__(256) void ln_kernel(const float* __restrict__ x,
                                                 const float* __restrict__ g,
                                                 const float* __restrict__ bta,
                                                 u16* __restrict__ xn) {
  int wave = threadIdx.x >> 6, lane = threadIdx.x & 63;
  long t = (long)blockIdx.x * 4 + wave;
  const float* xp = x + t * CH + lane * 8;
  f32x4 a = *(const f32x4*)xp;
  f32x4 b = *(const f32x4*)(xp + 4);
  float s  = a[0]+a[1]+a[2]+a[3]+b[0]+b[1]+b[2]+b[3];
  float sq = a[0]*a[0]+a[1]*a[1]+a[2]*a[2]+a[3]*a[3]+b[0]*b[0]+b[1]*b[1]+b[2]*b[2]+b[3]*b[3];
  for (int m = 1; m < 64; m <<= 1) { s += __shfl_xor(s, m); sq += __shfl_xor(sq, m); }
  float mu = s * (1.0f / 512.0f);
  float var = sq * (1.0f / 512.0f) - mu * mu;
  float rstd = rsqrtf(var + 1e-5f);
  const float* gp = g + lane * 8;
  const float* bp = bta + lane * 8;
  f32x4 g0 = *(const f32x4*)gp, g1 = *(const f32x4*)(gp + 4);
  f32x4 b0 = *(const f32x4*)bp, b1 = *(const f32x4*)(bp + 4);
  u16x8 o;
  o[0] = f2bf((a[0]-mu)*rstd*g0[0] + b0[0]);
  o[1] = f2bf((a[1]-mu)*rstd*g0[1] + b0[1]);
  o[2] = f2bf((a[2]-mu)*rstd*g0[2] + b0[2]);
  o[3] = f2bf((a[3]-mu)*rstd*g0[3] + b0[3]);
  o[4] = f2bf((b[0]-mu)*rstd*g1[0] + b1[0]);
  o[5] = f2bf((b[1]-mu)*rstd*g1[1] + b1[1]);
  o[6] = f2bf((b[2]-mu)*rstd*g1[2] + b1[2]);
  o[7] = f2bf((b[3]-mu)*rstd*g1[3] + b1[3]);
  *(u16x8*)(xn + t * CH + lane * 8) = o;
}

// ================= 8-phase 256x256 GEMM, K=512 fixed =================
template <int KT>
__device__ __forceinline__ void kstep8(char* sm, const u16* sA, const u16* sB,
                                       int t, int lane_off, int wm, int wn,
                                       f32x4 (&acc)[8][4]) {
  const char* base = sm + (KT & 3) * 32768 + lane_off;
  char* wbp = sm + ((KT + 3) & 3) * 32768 + t * 16;
  if constexpr (KT + 3 < 16) {
    load_lds16(sA + (KT + 3) * 32, wbp);
    load_lds16(sA + (KT + 3) * 32 + 65536, wbp + 8192);
  }
  bf16x8 bfr[4], afr[4];
#pragma unroll
  for (int n = 0; n < 4; n++) bfr[n] = *(const bf16x8*)(base + 16384 + wn * 4096 + n * 1024);
#pragma unroll
  for (int m = 0; m < 4; m++) afr[m] = *(const bf16x8*)(base + wm * 8192 + m * 1024);
  __builtin_amdgcn_s_barrier();
  __builtin_amdgcn_s_setprio(1);
#pragma unroll
  for (int m = 0; m < 4; m++)
#pragma unroll
    for (int n = 0; n < 4; n++)
      acc[m][n] = __builtin_amdgcn_mfma_f32_16x16x32_bf16(afr[m], bfr[n], acc[m][n], 0, 0, 0);
  __builtin_amdgcn_s_setprio(0);
  __builtin_amdgcn_s_barrier();
  if constexpr (KT + 3 < 16) {
    load_lds16(sB + (KT + 3) * 32, wbp + 16384);
    load_lds16(sB + (KT + 3) * 32 + 65536, wbp + 24576);
  }
#pragma unroll
  for (int m = 0; m < 4; m++) afr[m] = *(const bf16x8*)(base + wm * 8192 + (4 + m) * 1024);
  __builtin_amdgcn_s_barrier();
  __builtin_amdgcn_s_setprio(1);
#pragma unroll
  for (int m = 0; m < 4; m++)
#pragma unroll
    for (int n = 0; n < 4; n++)
      acc[4 + m][n] = __builtin_amdgcn_mfma_f32_16x16x32_bf16(afr[m], bfr[n], acc[4 + m][n], 0, 0, 0);
  __builtin_amdgcn_s_setprio(0);
  if constexpr (KT < 13) {
    asm volatile("s_waitcnt vmcnt(8)" ::: "memory");
  } else if constexpr (KT == 13) {
    asm volatile("s_waitcnt vmcnt(4)" ::: "memory");
  } else if constexpr (KT == 14) {
    asm volatile("s_waitcnt vmcnt(0)" ::: "memory");
  }
  if constexpr (KT < 15) __builtin_amdgcn_s_barrier();
}

// EPI: 0 = bf16 out, 1 = bf16 out with relu+1e-6 on cols<1024, 2 = f32 out + bias
template <int EPI>
__global__ __launch_bounds__(512, 2)
void gemm8(const u16* __restrict__ A, const u16* __restrict__ B,
           void* __restrict__ C, const float* __restrict__ bias, int N, int nbn) {
  __shared__ __align__(16) char sm[131072];
  const int nwg = gridDim.x;
  const int bid = blockIdx.x;
  const int cpx = nwg >> 3;
  const int vid = (bid & 7) * cpx + (bid >> 3);   // XCD-contiguous chunks
  const int bn = vid % nbn, bm = vid / nbn;
  const int t = threadIdx.x;
  const int lane = t & 63, wave = t >> 6;
  const int wm = wave >> 2, wn = wave & 3;
  const int fr = lane & 15, fq = lane >> 4;
  const int lane_off = (fr >> 1) * 128 + ((((fr & 1) << 2) + fq) ^ (fr >> 1)) * 16;
  const int sl = (t & 7) ^ ((t >> 3) & 7);
  const u16* sA = A + ((long)bm * 256 + ((t >> 3) << 1) + (sl >> 2)) * 512 + (sl & 3) * 8;
  const u16* sB = B + ((long)bn * 256 + ((t >> 3) << 1) + (sl >> 2)) * 512 + (sl & 3) * 8;
  f32x4 acc[8][4] = {};
#pragma unroll
  for (int kt = 0; kt < 3; kt++) {
    char* d = sm + kt * 32768 + t * 16;
    load_lds16(sA + kt * 32, d);
    load_lds16(sA + kt * 32 + 65536, d + 8192);
    load_lds16(sB + kt * 32, d + 16384);
    load_lds16(sB + kt * 32 + 65536, d + 24576);
  }
  asm volatile("s_waitcnt vmcnt(8)" ::: "memory");
  __builtin_amdgcn_s_barrier();
  kstep8<0>(sm, sA, sB, t, lane_off, wm, wn, acc);
  kstep8<1>(sm, sA, sB, t, lane_off, wm, wn, acc);
  kstep8<2>(sm, sA, sB, t, lane_off, wm, wn, acc);
  kstep8<3>(sm, sA, sB, t, lane_off, wm, wn, acc);
  kstep8<4>(sm, sA, sB, t, lane_off, wm, wn, acc);
  kstep8<5>(sm, sA, sB, t, lane_off, wm, wn, acc);
  kstep8<6>(sm, sA, sB, t, lane_off, wm, wn, acc);
  kstep8<7>(sm, sA, sB, t, lane_off, wm, wn, acc);
  kstep8<8>(sm, sA, sB, t, lane_off, wm, wn, acc);
  kstep8<9>(sm, sA, sB, t, lane_off, wm, wn, acc);
  kstep8<10>(sm, sA, sB, t, lane_off, wm, wn, acc);
  kstep8<11>(sm, sA, sB, t, lane_off, wm, wn, acc);
  kstep8<12>(sm, sA, sB, t, lane_off, wm, wn, acc);
  kstep8<13>(sm, sA, sB, t, lane_off, wm, wn, acc);
  kstep8<14>(sm, sA, sB, t, lane_off, wm, wn, acc);
  kstep8<15>(sm, sA, sB, t, lane_off, wm, wn, acc);
  const long r0 = (long)bm * 256 + wm * 128 + fq * 4;
  const int c0 = bn * 256 + wn * 64 + fr;
#pragma unroll
  for (int m = 0; m < 8; m++) {
#pragma unroll
    for (int n = 0; n < 4; n++) {
      int c = c0 + n * 16;
#pragma unroll
      for (int jj = 0; jj < 4; jj++) {
        long r = r0 + m * 16 + jj;
        float v = acc[m][n][jj];
        if (EPI == 1) {
          if (c < 1024) v = fmaxf(v, 0.0f) + 1e-6f;
          ((u16*)C)[r * N + c] = f2bf(v);
        } else if (EPI == 2) {
          ((float*)C)[r * N + c] = v + bias[c];
        } else {
          ((u16*)C)[r * N + c] = f2bf(v);
        }
      }
    }
  }
}

// ---------- m97-style B^T GEMM (kept for the mix GEMM) ----------
template <int EPI>
__global__ __launch_bounds__(256)
void gemm_bt(const u16* __restrict__ A, const u16* __restrict__ B,
             void* __restrict__ C, const float* __restrict__ bias,
             int M, int N, int K, long sAb, long sBb, long sCb) {
  __shared__ u16 As[128 * 32];
  __shared__ u16 Bs[128 * 32];
  const int tid = threadIdx.x;
  const int lane = tid & 63;
  const int wave = tid >> 6;
  const int fr = lane & 15, fq = lane >> 4;
  const int wr = (wave >> 1) * 64, wc = (wave & 1) * 64;
  const long bm = blockIdx.y, bn = blockIdx.x, bz = blockIdx.z;
  const u16* Ab = A + bz * sAb + bm * 128 * (long)K;
  const u16* Bb = B + bz * sBb + bn * 128 * (long)K;
  const int srow = tid >> 2;
  const int scol = (tid & 3) * 8;
  f32x4 acc[4][4] = {};
  for (int k0 = 0; k0 < K; k0 += 32) {
    load_lds16(Ab + (long)srow * K + k0 + scol, As + tid * 8);
    load_lds16(Ab + (long)(srow + 64) * K + k0 + scol, As + 2048 + tid * 8);
    load_lds16(Bb + (long)srow * K + k0 + scol, Bs + tid * 8);
    load_lds16(Bb + (long)(srow + 64) * K + k0 + scol, Bs + 2048 + tid * 8);
    __syncthreads();
    bf16x8 af[4], bf[4];
#pragma unroll
    for (int m = 0; m < 4; m++) af[m] = *(const bf16x8*)&As[(wr + m * 16 + fr) * 32 + fq * 8];
#pragma unroll
    for (int n = 0; n < 4; n++) bf[n] = *(const bf16x8*)&Bs[(wc + n * 16 + fr) * 32 + fq * 8];
#pragma unroll
    for (int m = 0; m < 4; m++)
#pragma unroll
      for (int n = 0; n < 4; n++)
        acc[m][n] = __builtin_amdgcn_mfma_f32_16x16x32_bf16(af[m], bf[n], acc[m][n], 0, 0, 0);
    __syncthreads();
  }
#pragma unroll
  for (int m = 0; m < 4; m++) {
    int r0 = wr + m * 16 + fq * 4;
#pragma unroll
    for (int n = 0; n < 4; n++) {
      int c = (int)bn * 128 + wc + n * 16 + fr;
#pragma unroll
      for (int jj = 0; jj < 4; jj++) {
        long r = bm * 128 + r0 + jj;
        float v = acc[m][n][jj];
        if (EPI == 1) { if (c < 1024) v = fmaxf(v, 0.0f) + 1e-6f; }
        if (EPI == 2) {
          ((float*)C)[bz * sCb + r * N + c] = v + bias[c];
        } else {
          ((u16*)C)[bz * sCb + r * N + c] = f2bf(v);
        }
      }
    }
  }
}

// ---------- fold v into zero-padded image [8][116][116][512] ----------
__global__ __launch_bounds__(256)
void fold_v(const u16* __restrict__ qkv, u16* __restrict__ vimg) {
  long i = (long)blockIdx.x * 256 + threadIdx.x;  // 25088 blocks
  int tok = (int)(i >> 6);
  int c0 = ((int)i & 63) * 8;
  int w = tok % WTOK, n = tok / WTOK;
  int b = n >> 8, blk = n & 255;
  int gi = blk >> 4, gj = blk & 15;
  int wi = w / 7, wj = w - wi * 7;
  int y = gi * 7 + wi + 2, x = gj * 7 + wj + 2;
  u16x8 v = *(const u16x8*)(qkv + (long)tok * CO + 1024 + c0);
  *(u16x8*)(vimg + (((long)(b * 116 + y)) * 116 + x) * 512 + c0) = v;
}

// zero the 2-wide border of vimg
__global__ __launch_bounds__(256)
void zero_border(u16* __restrict__ vimg) {
  int y = blockIdx.x, b = blockIdx.y;
  int tid = threadIdx.x;
  u16* row = vimg + ((long)(b * 116 + y)) * 116 * 512;
  u16x8 z = {};
  if (y < 2 || y >= 114) {
    for (int i = tid; i < 116 * 512 / 8; i += 256) *(u16x8*)(row + i * 8) = z;
  } else {
    int col = tid >> 6;
    int x = (col < 2) ? col : 112 + col;
    *(u16x8*)(row + x * 512 + (tid & 63) * 8) = z;
  }
}

// ---------- LePE depthwise 5x5: rolling register window, y-strip of 14 ----------
// thread: 4 channels (c0), 1 x; block: 2 x-positions x 512 ch; strip of 14 rows.
__global__ __launch_bounds__(256, 2)
void lepe_conv3(const u16* __restrict__ vimg, const float* __restrict__ wle,
                const float* __restrict__ lb, u16* __restrict__ lepe) {
  const int tid = threadIdx.x;
  const int c0 = (tid & 127) * 4;
  const int x  = blockIdx.x * 2 + (tid >> 7);   // 0..111
  const int ys = blockIdx.y * 14;               // strip start (multiple of 7)
  const int b  = blockIdx.z;
  // hoist all 25 weights (f32x4 each)
  f32x4 wv[25];
#pragma unroll
  for (int k = 0; k < 25; k++) wv[k] = *(const f32x4*)(wle + k * 512 + c0);
  const f32x4 bias = *(const f32x4*)(lb + c0);
  const u16* rbase = vimg + (((long)(b * 116 + ys)) * 116 + x) * 512 + c0;
  // rolling window: win[row%5][kx]
  u16x4 win[5][5];
#pragma unroll
  for (int j = 0; j < 4; j++) {
    const u16* rp = rbase + (long)j * (116 * 512);
#pragma unroll
    for (int kx = 0; kx < 5; kx++) win[j][kx] = *(const u16x4*)(rp + kx * 512);
  }
  const int gj = x / 7, wj = x - gj * 7;
  u16* ob = lepe + (((long)(b * 256 + blockIdx.y * 32 + gj)) * 49 + wj) * 512 + c0;
#pragma unroll
  for (int i = 0; i < 14; i++) {
    {
      const u16* rp = rbase + (long)(i + 4) * (116 * 512);
#pragma unroll
      for (int kx = 0; kx < 5; kx++) win[(i + 4) % 5][kx] = *(const u16x4*)(rp + kx * 512);
    }
    f32x4 acc = bias;
#pragma unroll
    for (int s = 0; s < 5; s++)
#pragma unroll
      for (int kx = 0; kx < 5; kx++) {
        u16x4 v = win[(i + s) % 5][kx];
        f32x4 w = wv[s * 5 + kx];
#pragma unroll
        for (int c = 0; c < 4; c++) acc[c] += bf2f(v[c]) * w[c];
      }
    u16x4 o;
#pragma unroll
    for (int c = 0; c < 4; c++) o[c] = f2bf(acc[c]);
    *(u16x4*)(ob + ((i / 7) * 784 + (i % 7) * 7) * 512) = o;
  }
}

// ---------- per-window k^T v (MFMA) + k_sum + q·k_sum ----------
__global__ __launch_bounds__(256)
void kv_local_kernel(const u16* __restrict__ qkv, u16* __restrict__ KVl,
                     float* __restrict__ qk_sum) {
  int n = blockIdx.x, h = blockIdx.y, b = blockIdx.z;
  int bh = b * HEADS + h;
  long tbase = ((long)(b * NB + n)) * WTOK;
  __shared__ u16 kT[64 * 72];
  __shared__ u16 vT[64 * 72];
  __shared__ u16 qs[49 * 72];
  __shared__ float ksum[64];
  __shared__ float qkp[256];
  int tid = threadIdx.x;
  for (int i = tid; i < (64 * 72) / 2; i += 256) {
    ((u32*)kT)[i] = 0;
    ((u32*)vT)[i] = 0;
  }
  __syncthreads();
  {
    int w = tid >> 3, d0 = (tid & 7) * 8;
    u16x8 k8 = *(const u16x8*)(qkv + (tbase + w) * CO + 512 + h * 64 + d0);
    u16x8 v8 = *(const u16x8*)(qkv + (tbase + w) * CO + 1024 + h * 64 + d0);
#pragma unroll
    for (int i = 0; i < 8; i++) { kT[(d0 + i) * 72 + w] = k8[i]; vT[(d0 + i) * 72 + w] = v8[i]; }
    int w2 = w + 32;
    if (w2 < WTOK) {
      u16x8 k82 = *(const u16x8*)(qkv + (tbase + w2) * CO + 512 + h * 64 + d0);
      u16x8 v82 = *(const u16x8*)(qkv + (tbase + w2) * CO + 1024 + h * 64 + d0);
#pragma unroll
      for (int i = 0; i < 8; i++) { kT[(d0 + i) * 72 + w2] = k82[i]; vT[(d0 + i) * 72 + w2] = v82[i]; }
    }
    if (tid < 196) {
      int wq = tid >> 2, dq = (tid & 3) * 16;
      u16x8 q0 = *(const u16x8*)(qkv + (tbase + wq) * CO + h * 64 + dq);
      u16x8 q1 = *(const u16x8*)(qkv + (tbase + wq) * CO + h * 64 + dq + 8);
      *(u16x8*)&qs[wq * 72 + dq] = q0;
      *(u16x8*)&qs[wq * 72 + dq + 8] = q1;
    }
  }
  __syncthreads();
  if (tid < 64) {
    float s = 0.0f;
#pragma unroll
    for (int c = 0; c < 9; c++) {
      u16x8 r = *(const u16x8*)&kT[tid * 72 + c * 8];
#pragma unroll
      for (int i = 0; i < 8; i++) s += bf2f(r[i]);
    }
    ksum[tid] = s;
  }
  __syncthreads();
  if (tid < 196) {
    int w = tid >> 2, d0 = (tid & 3) * 16;
    float s = 0.0f;
#pragma unroll
    for (int i = 0; i < 16; i++) s += bf2f(qs[w * 72 + d0 + i]) * ksum[d0 + i];
    qkp[tid] = s;
  }
  __syncthreads();
  if (tid < WTOK) {
    float s = qkp[tid * 4] + qkp[tid * 4 + 1] + qkp[tid * 4 + 2] + qkp[tid * 4 + 3];
    qk_sum[((long)bh * NB + n) * WTOK + tid] = s;
  }
  int lane = tid & 63, wave = tid >> 6;
  int fr = lane & 15, fq = lane >> 4;
  f32x4 acc[4] = {};
#pragma unroll
  for (int ks = 0; ks < 2; ks++) {
    bf16x8 a = *(const bf16x8*)&kT[(wave * 16 + fr) * 72 + ks * 32 + fq * 8];
#pragma unroll
    for (int n4 = 0; n4 < 4; n4++) {
      bf16x8 bb = *(const bf16x8*)&vT[(n4 * 16 + fr) * 72 + ks * 32 + fq * 8];
      acc[n4] = __builtin_amdgcn_mfma_f32_16x16x32_bf16(a, bb, acc[n4], 0, 0, 0);
    }
  }
  long obase = ((long)bh * NB + n) * 4096;
#pragma unroll
  for (int n4 = 0; n4 < 4; n4++)
#pragma unroll
    for (int jj = 0; jj < 4; jj++) {
      int d = wave * 16 + fq * 4 + jj;
      int e = n4 * 16 + fr;
      KVl[obase + d * 64 + e] = f2bf(acc[n4][jj]);
    }
}

// ---------- transpose KVl [bh][256][4096] -> KVT [bh][4096][256] ----------
__global__ __launch_bounds__(256)
void transpose_kv(const u16* __restrict__ in, u16* __restrict__ out) {
  int dt = blockIdx.x, jt = blockIdx.y, bh = blockIdx.z;
  __shared__ u16 t[64 * 72];
  int tid = threadIdx.x;
  {
    int jr = tid >> 2, c0 = (tid & 3) * 16;
    const u16* ip = in + ((long)bh * NB + jt * 64 + jr) * 4096 + dt * 64 + c0;
    *(u16x8*)&t[jr * 72 + c0] = *(const u16x8*)ip;
    *(u16x8*)&t[jr * 72 + c0 + 8] = *(const u16x8*)(ip + 8);
  }
  __syncthreads();
  {
    int der = tid >> 2, j0 = (tid & 3) * 16;
    u16x8 o0, o1;
#pragma unroll
    for (int i = 0; i < 8; i++) o0[i] = t[(j0 + i) * 72 + der];
#pragma unroll
    for (int i = 0; i < 8; i++) o1[i] = t[(j0 + 8 + i) * 72 + der];
    u16* op = out + ((long)bh * 4096 + dt * 64 + der) * 256 + jt * 64 + j0;
    *(u16x8*)op = o0;
    *(u16x8*)(op + 8) = o1;
  }
}

// ---------- normalizer: inv = 1/(Wt^T-mix of qk_sum + eps) ----------
__global__ __launch_bounds__(256)
void norm_kernel(const float* __restrict__ Wt, const float* __restrict__ qk_sum,
                 float* __restrict__ inv_norm) {
  int bh = blockIdx.x, tid = threadIdx.x;
  __shared__ float qk[NB * WTOK];
  for (int i = tid; i < NB * WTOK; i += 256) qk[i] = qk_sum[(long)bh * NB * WTOK + i];
  __syncthreads();
  float acc[WTOK];
#pragma unroll
  for (int w = 0; w < WTOK; w++) acc[w] = 0.0f;
  for (int j = 0; j < NB; j++) {
    float wv = Wt[j * NB + tid];
#pragma unroll
    for (int w = 0; w < WTOK; w++) acc[w] += wv * qk[j * WTOK + w];
  }
  long ob = ((long)bh * NB + tid) * WTOK;
#pragma unroll
  for (int w = 0; w < WTOK; w++) inv_norm[ob + w] = 1.0f / (acc[w] + 1e-6f);
}

// ---------- out = (q @ kvm) * inv_norm + lepe -> ebuf (bf16) ----------
__global__ __launch_bounds__(256)
void attn_out_kernel(const u16* __restrict__ qkv, const u16* __restrict__ kvm,
                     const float* __restrict__ inv_norm, const u16* __restrict__ lepe,
                     u16* __restrict__ ebuf) {
  int n = blockIdx.x, h = blockIdx.y, b = blockIdx.z;
  int bh = b * HEADS + h;
  long tbase = ((long)(b * NB + n)) * WTOK;
  __shared__ u16 qs[64 * 72];
  __shared__ u16 kvT[64 * 72];
  __shared__ float inv[WTOK];
  int tid = threadIdx.x;
  if (tid < 196) {
    int w = tid >> 2, d0 = (tid & 3) * 16;
    u16x8 q0 = *(const u16x8*)(qkv + (tbase + w) * CO + h * 64 + d0);
    u16x8 q1 = *(const u16x8*)(qkv + (tbase + w) * CO + h * 64 + d0 + 8);
    *(u16x8*)&qs[w * 72 + d0] = q0;
    *(u16x8*)&qs[w * 72 + d0 + 8] = q1;
  }
  {
    int d = tid >> 2, e0 = (tid & 3) * 16;
    const u16* kp = kvm + ((long)bh * NB + n) * 4096 + d * 64 + e0;
    u16x8 k0 = *(const u16x8*)kp;
    u16x8 k1 = *(const u16x8*)(kp + 8);
#pragma unroll
    for (int i = 0; i < 8; i++) { kvT[(e0 + i) * 72 + d] = k0[i]; kvT[(e0 + 8 + i) * 72 + d] = k1[i]; }
  }
  if (tid < WTOK) inv[tid] = inv_norm[((long)bh * NB + n) * WTOK + tid];
  __syncthreads();
  int lane = tid & 63, wave = tid >> 6;
  int fr = lane & 15, fq = lane >> 4;
  f32x4 acc[4] = {};
#pragma unroll
  for (int ks = 0; ks < 2; ks++) {
    bf16x8 a = *(const bf16x8*)&qs[(wave * 16 + fr) * 72 + ks * 32 + fq * 8];
#pragma unroll
    for (int n4 = 0; n4 < 4; n4++) {
      bf16x8 bb = *(const bf16x8*)&kvT[(n4 * 16 + fr) * 72 + ks * 32 + fq * 8];
      acc[n4] = __builtin_amdgcn_mfma_f32_16x16x32_bf16(a, bb, acc[n4], 0, 0, 0);
    }
  }
#pragma unroll
  for (int n4 = 0; n4 < 4; n4++)
#pragma unroll
    for (int jj = 0; jj < 4; jj++) {
      int w = wave * 16 + fq * 4 + jj;
      if (w < WTOK) {
        int e = n4 * 16 + fr;
        long off = (tbase + w) * CH + h * 64 + e;
        float v = acc[n4][jj] * inv[w] + bf2f(lepe[off]);
        ebuf[off] = f2bf(v);
      }
    }
}

// ---------- workspace layout ----------
static const size_t OFF_XN    = 0;                         // 102,760,448 (xn, then lepe)
static const size_t OFF_QKV   = 102760448;                 // 308,281,344
static const size_t OFF_KVL   = OFF_QKV + 308281344;       // 134,217,728 (KVl, then kvm)
static const size_t OFF_KVT   = OFF_KVL + 134217728;       // 134,217,728 (vimg, then KVT, then ebuf)
static const size_t OFF_QKS   = OFF_KVT + 134217728;       // 3,211,264
static const size_t OFF_INV   = OFF_QKS + 3211264;         // 3,211,264
static const size_t OFF_WBF   = OFF_INV + 3211264;         // 131,072
static const size_t OFF_WTF   = OFF_WBF + 131072;          // 262,144
static const size_t OFF_WQKVB = OFF_WTF + 262144;          // 1,572,864
static const size_t OFF_WOUTB = OFF_WQKVB + 1572864;       // 524,288
static const size_t OFF_WLE   = OFF_WOUTB + 524288;        // 51,200

extern "C" void kernel_launch(void* const* d_in, const int* in_sizes, int n_in,
                              void* d_out, int out_size, void* d_ws, size_t ws_size,
                              hipStream_t stream) {
  const float* x      = (const float*)d_in[0];
  const float* ln_g   = (const float*)d_in[1];
  const float* ln_b   = (const float*)d_in[2];
  const float* w_qkv  = (const float*)d_in[3];
  const float* lepe_w = (const float*)d_in[4];
  const float* lepe_b = (const float*)d_in[5];
  const float* w_out  = (const float*)d_in[6];
  const float* b_out  = (const float*)d_in[7];
  float* out = (float*)d_out;
  char* ws = (char*)d_ws;

  u16*   xn     = (u16*)(ws + OFF_XN);
  u16*   lepe   = (u16*)(ws + OFF_XN);     // reuse after GEMM1
  u16*   qkv    = (u16*)(ws + OFF_QKV);
  u16*   KVl    = (u16*)(ws + OFF_KVL);
  u16*   kvm    = (u16*)(ws + OFF_KVL);    // reuse after transpose
  u16*   vimg   = (u16*)(ws + OFF_KVT);    // padded v image (110 MB), dead after lepe_conv3
  u16*   KVT    = (u16*)(ws + OFF_KVT);
  u16*   ebuf   = (u16*)(ws + OFF_KVT);    // reuse after mix
  float* qks    = (float*)(ws + OFF_QKS);
  float* invn   = (float*)(ws + OFF_INV);
  u16*   Wbf    = (u16*)(ws + OFF_WBF);
  float* Wt     = (float*)(ws + OFF_WTF);
  u16*   wqkvb  = (u16*)(ws + OFF_WQKVB);
  u16*   woutb  = (u16*)(ws + OFF_WOUTB);
  float* wle    = (float*)(ws + OFF_WLE);

  cvt_f32_bf16<<<384, 256, 0, stream>>>(w_qkv, wqkvb, 98304);
  cvt_f32_bf16<<<128, 256, 0, stream>>>(w_out, woutb, 32768);
  prep_wle<<<50, 256, 0, stream>>>(lepe_w, wle);
  weight_kernel<<<256, 256, 0, stream>>>(Wbf, Wt);
  zero_border<<<dim3(116, 8), 256, 0, stream>>>(vimg);

  ln_kernel<<<25088, 256, 0, stream>>>(x, ln_g, ln_b, xn);

  // qkv = xn @ w_qkv^T, relu+eps on q,k   (8-phase 256x256, K=512)
  gemm8<1><<<2352, 512, 0, stream>>>(xn, wqkvb, (void*)qkv, nullptr, CO, 6);

  fold_v<<<25088, 256, 0, stream>>>(qkv, vimg);
  lepe_conv3<<<dim3(56, 8, 8), 256, 0, stream>>>(vimg, wle, lepe_b, lepe);

  kv_local_kernel<<<dim3(NB, HEADS, 8), 256, 0, stream>>>(qkv, KVl, qks);

  transpose_kv<<<dim3(64, 4, 64), 256, 0, stream>>>(KVl, KVT);

  // kvm[bh] = W @ KV[bh]  (bt-GEMM: A=W [256,256], B=KVT [4096,256])
  gemm_bt<0><<<dim3(32, 2, 64), 256, 0, stream>>>(Wbf, KVT, (void*)kvm, nullptr,
                                                  NB, 4096, NB,
                                                  0, (long)4096 * 256, (long)256 * 4096);

  norm_kernel<<<64, 256, 0, stream>>>(Wt, qks, invn);

  attn_out_kernel<<<dim3(NB, HEADS, 8), 256, 0, stream>>>(qkv, kvm, invn, lepe, ebuf);

  // final projection: out = ebuf @ w_out^T + b_out (fp32 out, 8-phase)
  gemm8<2><<<784, 512, 0, stream>>>(ebuf, woutb, (void*)out, b_out, CH, 2);
}